// Round 8
// baseline (783.216 us; speedup 1.0000x reference)
//
#include <hip/hip_runtime.h>
#include <hip/hip_bf16.h>
#include <cstdint>
#include <cstddef>

#define N_NODES 50000
#define N_EDGES 1600000
#define HID 128
#define PCAT_N 384
#define EPSV 1e-12f

typedef __bf16 bf16_t;
typedef __bf16 bf16x8 __attribute__((ext_vector_type(8)));
typedef float f32x4 __attribute__((ext_vector_type(4)));

__device__ __forceinline__ float bf2f_lo(unsigned u) {
    return __builtin_bit_cast(float, u << 16);
}
__device__ __forceinline__ float bf2f_hi(unsigned u) {
    return __builtin_bit_cast(float, u & 0xFFFF0000u);
}
__device__ __forceinline__ unsigned short f2bf_rne(float x) {
    unsigned u = __builtin_bit_cast(unsigned, x);
    u += 0x7FFFu + ((u >> 16) & 1u);
    return (unsigned short)(u >> 16);
}
// silu via fast rcp (v_rcp_f32) instead of IEEE division
__device__ __forceinline__ float silu_f(float x) {
    return x * __builtin_amdgcn_rcpf(1.0f + __expf(-x));
}

// ---------------------------------------------------------------------------
// Prep: bf16 transposed weight blocks.
// wcatT[n][k], n<128 -> W1a^T, n<256 -> W1b^T, else Wv^T.  w2t[n][k]=W2[k][n].
// ---------------------------------------------------------------------------
__global__ void k_prepw(const float* __restrict__ W1, const float* __restrict__ W2,
                        const float* __restrict__ Wv, bf16_t* __restrict__ wcatT,
                        bf16_t* __restrict__ w2t) {
    int idx = blockIdx.x * blockDim.x + threadIdx.x;
    if (idx < 384 * 128) {
        int n = idx >> 7, k = idx & 127;
        float v;
        if (n < 128)      v = W1[k * 128 + n];
        else if (n < 256) v = W1[(128 + k) * 128 + (n - 128)];
        else              v = Wv[k * 128 + (n - 256)];
        wcatT[idx] = __builtin_bit_cast(bf16_t, f2bf_rne(v));
    } else if (idx < 384 * 128 + 128 * 128) {
        int j = idx - 384 * 128;
        int n = j >> 7, k = j & 127;
        w2t[j] = __builtin_bit_cast(bf16_t, f2bf_rne(W2[k * 128 + n]));
    }
}

// ---------------------------------------------------------------------------
// Node projection: pcat[i][0:384] = bf16( h[i] @ [W1a | W1b | Wv] ),
// value cols (>=256) pre-scaled by node_weight[i].
// ---------------------------------------------------------------------------
__global__ __launch_bounds__(256) void k_nodeproj(
    const float* __restrict__ h, const bf16_t* __restrict__ wcatT,
    const float* __restrict__ nw, bf16_t* __restrict__ pcat) {
    __shared__ bf16_t As[64 * 136];
    int t = threadIdx.x;
    int r0 = blockIdx.x * 64;
    {
        int r = t >> 2, cbase = (t & 3) * 32;
        int gr = r0 + r;
        if (gr >= N_NODES) gr = 0;
        const float* src = h + (size_t)gr * 128 + cbase;
        bf16_t* dst = As + r * 136 + cbase;
#pragma unroll
        for (int i = 0; i < 4; ++i) {
            float4 v0 = *reinterpret_cast<const float4*>(src + i * 8);
            float4 v1 = *reinterpret_cast<const float4*>(src + i * 8 + 4);
            uint4 pk;
            pk.x = (unsigned)f2bf_rne(v0.x) | ((unsigned)f2bf_rne(v0.y) << 16);
            pk.y = (unsigned)f2bf_rne(v0.z) | ((unsigned)f2bf_rne(v0.w) << 16);
            pk.z = (unsigned)f2bf_rne(v1.x) | ((unsigned)f2bf_rne(v1.y) << 16);
            pk.w = (unsigned)f2bf_rne(v1.z) | ((unsigned)f2bf_rne(v1.w) << 16);
            *reinterpret_cast<uint4*>(dst + i * 8) = pk;
        }
    }
    __syncthreads();
    int lane = t & 63, w = t >> 6;
    f32x4 acc[4][6] = {};
#pragma unroll
    for (int kk = 0; kk < 4; ++kk) {
        bf16x8 af[4], bfr[6];
#pragma unroll
        for (int fm = 0; fm < 4; ++fm)
            af[fm] = *reinterpret_cast<const bf16x8*>(
                As + (fm * 16 + (lane & 15)) * 136 + kk * 32 + (lane >> 4) * 8);
#pragma unroll
        for (int fn = 0; fn < 6; ++fn) {
            int n = w * 96 + fn * 16 + (lane & 15);
            bfr[fn] = *reinterpret_cast<const bf16x8*>(
                wcatT + (size_t)n * 128 + kk * 32 + (lane >> 4) * 8);
        }
#pragma unroll
        for (int fm = 0; fm < 4; ++fm)
#pragma unroll
            for (int fn = 0; fn < 6; ++fn)
                acc[fm][fn] = __builtin_amdgcn_mfma_f32_16x16x32_bf16(
                    af[fm], bfr[fn], acc[fm][fn], 0, 0, 0);
    }
#pragma unroll
    for (int fm = 0; fm < 4; ++fm) {
#pragma unroll
        for (int j = 0; j < 4; ++j) {
            int row = r0 + fm * 16 + (lane >> 4) * 4 + j;
            if (row < N_NODES) {
                float nwv = (w >= 2) ? nw[row] : 1.0f;
#pragma unroll
                for (int fn = 0; fn < 6; ++fn) {
                    int colbase = w * 96 + fn * 16;
                    float v = acc[fm][fn][j];
                    if (colbase >= 256) v *= nwv;
                    pcat[(size_t)row * PCAT_N + colbase + (lane & 15)] =
                        __builtin_bit_cast(bf16_t, f2bf_rne(v));
                }
            }
        }
    }
}

// ---------------------------------------------------------------------------
// CSR build: hist -> scan -> scatter (CSR-ordered packed edge records)
// rec = { bf16(rp0)|bf16(rp1)<<16, bf16(rp2)|bf16(dist)<<16, dst, src }
// ---------------------------------------------------------------------------
__global__ void k_hist(const int* __restrict__ eidx, int* __restrict__ hist) {
    int stride = gridDim.x * blockDim.x;
    for (int e = blockIdx.x * blockDim.x + threadIdx.x; e < N_EDGES; e += stride)
        atomicAdd(&hist[eidx[e]], 1);
}

__global__ __launch_bounds__(1024) void k_scan(const int* __restrict__ hist,
                                               int* __restrict__ row_start,
                                               int* __restrict__ cursor,
                                               float* __restrict__ den) {
    __shared__ int partial[1024];
    int t = threadIdx.x;
    const int C = (N_NODES + 1023) / 1024;  // 49
    int base = t * C;
    int sum = 0;
    for (int i = 0; i < C; ++i) {
        int j = base + i;
        if (j < N_NODES) sum += hist[j];
    }
    partial[t] = sum;
    __syncthreads();
    for (int off = 1; off < 1024; off <<= 1) {
        int v = (t >= off) ? partial[t - off] : 0;
        __syncthreads();
        partial[t] += v;
        __syncthreads();
    }
    int run = partial[t] - sum;  // exclusive prefix
    for (int i = 0; i < C; ++i) {
        int j = base + i;
        if (j < N_NODES) {
            row_start[j] = run;
            cursor[j] = run;
            den[j] = 0.0f;
            run += hist[j];
        }
    }
    if (t == 1023) row_start[N_NODES] = partial[1023];
}

__global__ void k_scatter(const int* __restrict__ eidx,
                          const float* __restrict__ rel_pos,
                          const float* __restrict__ dist,
                          int* __restrict__ cursor,
                          uint4* __restrict__ recs) {
    int stride = gridDim.x * blockDim.x;
    for (int e = blockIdx.x * blockDim.x + threadIdx.x; e < N_EDGES; e += stride) {
        int d = eidx[e];
        int sv = eidx[N_EDGES + e];
        float r0 = rel_pos[(size_t)e * 3];
        float r1 = rel_pos[(size_t)e * 3 + 1];
        float r2 = rel_pos[(size_t)e * 3 + 2];
        float dd = dist[e];
        uint4 rec;
        rec.x = (unsigned)f2bf_rne(r0) | ((unsigned)f2bf_rne(r1) << 16);
        rec.y = (unsigned)f2bf_rne(r2) | ((unsigned)f2bf_rne(dd) << 16);
        rec.z = (unsigned)d;
        rec.w = (unsigned)sv;
        int pos = atomicAdd(&cursor[d], 1);
        recs[pos] = rec;
    }
}

// ---------------------------------------------------------------------------
// Fully fused edge kernel, CSR-ordered (64 edges/block, 256 threads).
// phase0: coalesced 16B record load for the 64 CSR slots (dst-sorted runs).
// phase1: X1 = silu(Pa[dst]+Pb[src]+rp-term+b1) -> LDS.
// phase2: layer2 MFMA (W2 frags from L2-resident global).
// phase3: layer3 dot -> s_sc (LDS atomics).
// phase5: per dst-run: acc += exp(score)*hv[src]; one atomic row-flush per
//         (node, block) into out (numerator); one den atomic per run.
// ---------------------------------------------------------------------------
__global__ __launch_bounds__(256, 6) void k_fused(
    const bf16_t* __restrict__ pcat, const bf16_t* __restrict__ w2t,
    const uint4* __restrict__ recs, const float* __restrict__ W1,
    const float* __restrict__ b1, const float* __restrict__ b2,
    const float* __restrict__ W3, const float* __restrict__ b3,
    float* __restrict__ den, float* __restrict__ outp) {
    __shared__ bf16_t Ax[64 * 136];
    __shared__ int s_dst[64];
    __shared__ int s_src[64];
    __shared__ float4 s_rp[64];
    __shared__ float s_sc[64];
    __shared__ int s_runstart[65];
    __shared__ int s_runnode[64];
    __shared__ int s_nruns;

    int t = threadIdx.x;
    int e0 = blockIdx.x * 64;
    if (t < 64) {
        uint4 rec = recs[e0 + t];
        s_dst[t] = (int)rec.z;
        s_src[t] = (int)rec.w;
        s_rp[t] = make_float4(bf2f_lo(rec.x), bf2f_hi(rec.x),
                              bf2f_lo(rec.y), bf2f_hi(rec.y));
        s_sc[t] = b3[0];
    }
    int lane = t & 63, w = t >> 6;
    int c0 = 2 * lane;
    float wA0 = W1[256 * 128 + c0], wA1 = W1[257 * 128 + c0];
    float wA2 = W1[258 * 128 + c0], wA3 = W1[259 * 128 + c0];
    float bA = b1[c0];
    float wB0 = W1[256 * 128 + c0 + 1], wB1 = W1[257 * 128 + c0 + 1];
    float wB2 = W1[258 * 128 + c0 + 1], wB3 = W1[259 * 128 + c0 + 1];
    float bB = b1[c0 + 1];
    __syncthreads();

    // run structure (dst is sorted within the block): one ballot in wave 0
    if (t < 64) {
        bool flag = (t == 0) || (s_dst[t] != s_dst[t - 1]);
        unsigned long long mask = __ballot((int)flag);
        int rid = (int)__popcll(mask & ((2ull << t) - 1)) - 1;
        if (flag) {
            s_runstart[rid] = t;
            s_runnode[rid] = s_dst[t];
        }
        if (t == 0) {
            int nr = (int)__popcll(mask);
            s_nruns = nr;
            s_runstart[nr] = 64;
        }
    }

    // phase 1: wave w assembles edges [w*16, w*16+16)
#pragma unroll 4
    for (int i = 0; i < 16; ++i) {
        int e = w * 16 + i;
        int dn = s_dst[e], sn = s_src[e];
        float4 rp = s_rp[e];
        unsigned pa = *reinterpret_cast<const unsigned*>(pcat + (size_t)dn * PCAT_N + c0);
        unsigned pb = *reinterpret_cast<const unsigned*>(pcat + (size_t)sn * PCAT_N + 128 + c0);
        float x0 = bf2f_lo(pa) + bf2f_lo(pb) +
                   rp.x * wA0 + rp.y * wA1 + rp.z * wA2 + rp.w * wA3 + bA;
        float x1 = bf2f_hi(pa) + bf2f_hi(pb) +
                   rp.x * wB0 + rp.y * wB1 + rp.z * wB2 + rp.w * wB3 + bB;
        float y0 = silu_f(x0), y1 = silu_f(x1);
        unsigned pk = (unsigned)f2bf_rne(y0) | ((unsigned)f2bf_rne(y1) << 16);
        *reinterpret_cast<unsigned*>(Ax + e * 136 + c0) = pk;
    }
    __syncthreads();

    // phase 2: wave w computes cols [w*32, w*32+32) for all 64 edges
    f32x4 acc[4][2] = {};
#pragma unroll
    for (int kk = 0; kk < 4; ++kk) {
        bf16x8 af[4], bfr[2];
#pragma unroll
        for (int fn = 0; fn < 2; ++fn) {
            int n = w * 32 + fn * 16 + (lane & 15);
            bfr[fn] = *reinterpret_cast<const bf16x8*>(
                w2t + (size_t)n * 128 + kk * 32 + (lane >> 4) * 8);
        }
#pragma unroll
        for (int fm = 0; fm < 4; ++fm)
            af[fm] = *reinterpret_cast<const bf16x8*>(
                Ax + (fm * 16 + (lane & 15)) * 136 + kk * 32 + (lane >> 4) * 8);
#pragma unroll
        for (int fm = 0; fm < 4; ++fm)
#pragma unroll
            for (int fn = 0; fn < 2; ++fn)
                acc[fm][fn] = __builtin_amdgcn_mfma_f32_16x16x32_bf16(
                    af[fm], bfr[fn], acc[fm][fn], 0, 0, 0);
    }

    // phase 3: layer3 (silu + dot W3), 16-lane reduce, LDS combine
    float w3v[2], b2v[2];
#pragma unroll
    for (int fn = 0; fn < 2; ++fn) {
        int n = w * 32 + fn * 16 + (lane & 15);
        w3v[fn] = W3[n];
        b2v[fn] = b2[n];
    }
#pragma unroll
    for (int fm = 0; fm < 4; ++fm) {
        float pj[4] = {0.f, 0.f, 0.f, 0.f};
#pragma unroll
        for (int fn = 0; fn < 2; ++fn) {
#pragma unroll
            for (int j = 0; j < 4; ++j)
                pj[j] += silu_f(acc[fm][fn][j] + b2v[fn]) * w3v[fn];
        }
#pragma unroll
        for (int j = 0; j < 4; ++j) {
            float v = pj[j];
            v += __shfl_xor(v, 1);
            v += __shfl_xor(v, 2);
            v += __shfl_xor(v, 4);
            v += __shfl_xor(v, 8);
            if ((lane & 15) == 0)
                atomicAdd(&s_sc[fm * 16 + (lane >> 4) * 4 + j], v);
        }
    }
    __syncthreads();

    // phase 5: aggregation over dst-runs; wave w takes runs w, w+4, ...
    int nruns = s_nruns;
    for (int r = w; r < nruns; r += 4) {
        int node = s_runnode[r];
        int j0 = s_runstart[r], j1 = s_runstart[r + 1];
        float a0 = 0.f, a1 = 0.f, ad = 0.f;
        for (int j = j0; j < j1; ++j) {
            float c = __expf(s_sc[j]);   // broadcast LDS read
            int sv = s_src[j];
            unsigned hv = *reinterpret_cast<const unsigned*>(
                pcat + (size_t)sv * PCAT_N + 256 + c0);
            a0 += c * bf2f_lo(hv);
            a1 += c * bf2f_hi(hv);
            ad += c;
        }
        atomicAdd(&outp[(size_t)node * 128 + c0], a0);
        atomicAdd(&outp[(size_t)node * 128 + c0 + 1], a1);
        if (lane == 0) atomicAdd(&den[node], ad);
    }
}

// ---------------------------------------------------------------------------
// Normalize (in place): out = h + out * rcp(den[node]+eps)
// ---------------------------------------------------------------------------
__global__ __launch_bounds__(256) void k_norm(const float* __restrict__ h,
                                              const float* __restrict__ den,
                                              float* __restrict__ outp) {
    int idx = blockIdx.x * 256 + threadIdx.x;  // one float2 per thread
    int node = idx >> 6;
    float inv = __builtin_amdgcn_rcpf(den[node] + EPSV);
    float2 n2 = *reinterpret_cast<const float2*>(outp + (size_t)idx * 2);
    float2 h2 = *reinterpret_cast<const float2*>(h + (size_t)idx * 2);
    float2 res;
    res.x = h2.x + n2.x * inv;
    res.y = h2.y + n2.y * inv;
    *reinterpret_cast<float2*>(outp + (size_t)idx * 2) = res;
}

// ---------------------------------------------------------------------------
extern "C" void kernel_launch(void* const* d_in, const int* in_sizes, int n_in,
                              void* d_out, int out_size, void* d_ws, size_t ws_size,
                              hipStream_t stream) {
    const float* h       = (const float*)d_in[0];
    const int*   eidx    = (const int*)d_in[1];
    const float* rel_pos = (const float*)d_in[2];
    const float* dist    = (const float*)d_in[3];
    const float* nw      = (const float*)d_in[4];
    const float* W1      = (const float*)d_in[5];
    const float* b1      = (const float*)d_in[6];
    const float* W2      = (const float*)d_in[7];
    const float* b2      = (const float*)d_in[8];
    const float* W3      = (const float*)d_in[9];
    const float* b3      = (const float*)d_in[10];
    const float* Wv      = (const float*)d_in[11];
    float* out = (float*)d_out;

    char* p = (char*)d_ws;
    auto carve = [&](size_t bytes) {
        char* r = p;
        p += (bytes + 255) & ~(size_t)255;
        return r;
    };
    bf16_t* pcat    = (bf16_t*)carve((size_t)N_NODES * PCAT_N * 2);
    bf16_t* wcatT   = (bf16_t*)carve(384 * 128 * 2);
    bf16_t* w2t     = (bf16_t*)carve(128 * 128 * 2);
    uint4* recs     = (uint4*)carve((size_t)N_EDGES * 16);
    int* hist       = (int*)carve((size_t)N_NODES * 4);
    int* row_start  = (int*)carve((size_t)(N_NODES + 1) * 4);
    int* cursor     = (int*)carve((size_t)N_NODES * 4);
    float* den      = (float*)carve((size_t)N_NODES * 4);

    hipMemsetAsync(hist, 0, (size_t)N_NODES * 4, stream);
    hipMemsetAsync(out, 0, (size_t)N_NODES * HID * 4, stream);
    k_prepw<<<256, 256, 0, stream>>>(W1, W2, Wv, wcatT, w2t);
    k_nodeproj<<<(N_NODES + 63) / 64, 256, 0, stream>>>(h, wcatT, nw, pcat);
    k_hist<<<2048, 256, 0, stream>>>(eidx, hist);
    k_scan<<<1, 1024, 0, stream>>>(hist, row_start, cursor, den);
    k_scatter<<<2048, 256, 0, stream>>>(eidx, rel_pos, dist, cursor, recs);
    k_fused<<<N_EDGES / 64, 256, 0, stream>>>(pcat, w2t, recs, W1, b1, b2,
                                              W3, b3, den, out);
    k_norm<<<(N_NODES * HID / 2) / 256, 256, 0, stream>>>(h, den, out);
}

// Round 10
// 706.683 us; speedup vs baseline: 1.1083x; 1.1083x over previous
//
#include <hip/hip_runtime.h>
#include <hip/hip_bf16.h>
#include <cstdint>
#include <cstddef>

#define N_NODES 50000
#define N_EDGES 1600000
#define HID 128
#define PCAT_N 384
#define EPSV 1e-12f

typedef __bf16 bf16_t;
typedef __bf16 bf16x8 __attribute__((ext_vector_type(8)));
typedef float f32x4 __attribute__((ext_vector_type(4)));

__device__ __forceinline__ float bf2f_lo(unsigned u) {
    return __builtin_bit_cast(float, u << 16);
}
__device__ __forceinline__ float bf2f_hi(unsigned u) {
    return __builtin_bit_cast(float, u & 0xFFFF0000u);
}
__device__ __forceinline__ unsigned short f2bf_rne(float x) {
    unsigned u = __builtin_bit_cast(unsigned, x);
    u += 0x7FFFu + ((u >> 16) & 1u);
    return (unsigned short)(u >> 16);
}
// silu via fast rcp (v_rcp_f32) instead of IEEE division
__device__ __forceinline__ float silu_f(float x) {
    return x * __builtin_amdgcn_rcpf(1.0f + __expf(-x));
}
// manual fp8 e4m3 encode (RNE, denorm->0, clamp 448) / decode — round-trip pair
__device__ __forceinline__ unsigned enc_fp8(float x) {
    unsigned u = __builtin_bit_cast(unsigned, x);
    unsigned s = (u >> 24) & 0x80u;
    unsigned mag = u & 0x7FFFFFFFu;
    if (mag > 0x43E00000u) mag = 0x43E00000u;  // clamp to 448
    if (mag < 0x3C800000u) return s;           // |x| < 2^-6 -> signed zero
    unsigned r = mag + 0x7FFFFu + ((mag >> 20) & 1u);  // RNE at bit 20
    unsigned e = (r >> 23) - 120u;             // 1..15
    unsigned m = (r >> 20) & 7u;
    return s | (e << 3) | m;
}
__device__ __forceinline__ float dec_fp8(unsigned c) {
    unsigned e = (c >> 3) & 0xFu;
    unsigned u = ((c & 0x80u) << 24) | ((e + 120u) << 23) | ((c & 7u) << 20);
    return e ? __builtin_bit_cast(float, u) : 0.0f;
}

// ---------------------------------------------------------------------------
// Prep: bf16 transposed weight blocks.
// wcatT[n][k], n<128 -> W1a^T, n<256 -> W1b^T, else Wv^T.  w2t[n][k]=W2[k][n].
// ---------------------------------------------------------------------------
__global__ void k_prepw(const float* __restrict__ W1, const float* __restrict__ W2,
                        const float* __restrict__ Wv, bf16_t* __restrict__ wcatT,
                        bf16_t* __restrict__ w2t) {
    int idx = blockIdx.x * blockDim.x + threadIdx.x;
    if (idx < 384 * 128) {
        int n = idx >> 7, k = idx & 127;
        float v;
        if (n < 128)      v = W1[k * 128 + n];
        else if (n < 256) v = W1[(128 + k) * 128 + (n - 128)];
        else              v = Wv[k * 128 + (n - 256)];
        wcatT[idx] = __builtin_bit_cast(bf16_t, f2bf_rne(v));
    } else if (idx < 384 * 128 + 128 * 128) {
        int j = idx - 384 * 128;
        int n = j >> 7, k = j & 127;
        w2t[j] = __builtin_bit_cast(bf16_t, f2bf_rne(W2[k * 128 + n]));
    }
}

// ---------------------------------------------------------------------------
// Node projection + (fused) dst histogram.
// pcat[i][0:384] = bf16( h[i] @ [W1a | W1b | Wv] ), value cols nw-scaled.
// ---------------------------------------------------------------------------
__global__ __launch_bounds__(256) void k_nodeproj(
    const float* __restrict__ h, const bf16_t* __restrict__ wcatT,
    const float* __restrict__ nw, bf16_t* __restrict__ pcat,
    const int* __restrict__ eidx, int* __restrict__ hist) {
    __shared__ bf16_t As[64 * 136];
    int t = threadIdx.x;
    int r0 = blockIdx.x * 64;
    {
        int r = t >> 2, cbase = (t & 3) * 32;
        int gr = r0 + r;
        if (gr >= N_NODES) gr = 0;
        const float* src = h + (size_t)gr * 128 + cbase;
        bf16_t* dst = As + r * 136 + cbase;
#pragma unroll
        for (int i = 0; i < 4; ++i) {
            float4 v0 = *reinterpret_cast<const float4*>(src + i * 8);
            float4 v1 = *reinterpret_cast<const float4*>(src + i * 8 + 4);
            uint4 pk;
            pk.x = (unsigned)f2bf_rne(v0.x) | ((unsigned)f2bf_rne(v0.y) << 16);
            pk.y = (unsigned)f2bf_rne(v0.z) | ((unsigned)f2bf_rne(v0.w) << 16);
            pk.z = (unsigned)f2bf_rne(v1.x) | ((unsigned)f2bf_rne(v1.y) << 16);
            pk.w = (unsigned)f2bf_rne(v1.z) | ((unsigned)f2bf_rne(v1.w) << 16);
            *reinterpret_cast<uint4*>(dst + i * 8) = pk;
        }
    }
    __syncthreads();
    int lane = t & 63, w = t >> 6;
    f32x4 acc[4][6] = {};
#pragma unroll
    for (int kk = 0; kk < 4; ++kk) {
        bf16x8 af[4], bfr[6];
#pragma unroll
        for (int fm = 0; fm < 4; ++fm)
            af[fm] = *reinterpret_cast<const bf16x8*>(
                As + (fm * 16 + (lane & 15)) * 136 + kk * 32 + (lane >> 4) * 8);
#pragma unroll
        for (int fn = 0; fn < 6; ++fn) {
            int n = w * 96 + fn * 16 + (lane & 15);
            bfr[fn] = *reinterpret_cast<const bf16x8*>(
                wcatT + (size_t)n * 128 + kk * 32 + (lane >> 4) * 8);
        }
#pragma unroll
        for (int fm = 0; fm < 4; ++fm)
#pragma unroll
            for (int fn = 0; fn < 6; ++fn)
                acc[fm][fn] = __builtin_amdgcn_mfma_f32_16x16x32_bf16(
                    af[fm], bfr[fn], acc[fm][fn], 0, 0, 0);
    }
#pragma unroll
    for (int fm = 0; fm < 4; ++fm) {
#pragma unroll
        for (int j = 0; j < 4; ++j) {
            int row = r0 + fm * 16 + (lane >> 4) * 4 + j;
            if (row < N_NODES) {
                float nwv = (w >= 2) ? nw[row] : 1.0f;
#pragma unroll
                for (int fn = 0; fn < 6; ++fn) {
                    int colbase = w * 96 + fn * 16;
                    float v = acc[fm][fn][j];
                    if (colbase >= 256) v *= nwv;
                    pcat[(size_t)row * PCAT_N + colbase + (lane & 15)] =
                        __builtin_bit_cast(bf16_t, f2bf_rne(v));
                }
            }
        }
    }
    // fused histogram pass (overlaps other blocks' GEMMs)
    int stride = gridDim.x * 256;
    for (int e = blockIdx.x * 256 + t; e < N_EDGES; e += stride)
        atomicAdd(&hist[eidx[e]], 1);
}

// ---------------------------------------------------------------------------
// Scan: cursor = exclusive prefix of hist; den zeroed.
// ---------------------------------------------------------------------------
__global__ __launch_bounds__(1024) void k_scan(const int* __restrict__ hist,
                                               int* __restrict__ cursor,
                                               float* __restrict__ den) {
    __shared__ int partial[1024];
    int t = threadIdx.x;
    const int C = (N_NODES + 1023) / 1024;  // 49
    int base = t * C;
    int sum = 0;
    for (int i = 0; i < C; ++i) {
        int j = base + i;
        if (j < N_NODES) sum += hist[j];
    }
    partial[t] = sum;
    __syncthreads();
    for (int off = 1; off < 1024; off <<= 1) {
        int v = (t >= off) ? partial[t - off] : 0;
        __syncthreads();
        partial[t] += v;
        __syncthreads();
    }
    int run = partial[t] - sum;  // exclusive prefix
    for (int i = 0; i < C; ++i) {
        int j = base + i;
        if (j < N_NODES) {
            cursor[j] = run;
            den[j] = 0.0f;
            run += hist[j];
        }
    }
}

// ---------------------------------------------------------------------------
// Scatter: 8B CSR-ordered records {u32 dst<<16|src, u32 4xfp8 rp0,rp1,rp2,d}
// ---------------------------------------------------------------------------
__global__ void k_scatter(const int* __restrict__ eidx,
                          const float* __restrict__ rel_pos,
                          const float* __restrict__ dist,
                          int* __restrict__ cursor,
                          uint2* __restrict__ recs) {
    int stride = gridDim.x * blockDim.x;
    for (int e = blockIdx.x * blockDim.x + threadIdx.x; e < N_EDGES; e += stride) {
        int d = eidx[e];
        int sv = eidx[N_EDGES + e];
        float r0 = rel_pos[(size_t)e * 3];
        float r1 = rel_pos[(size_t)e * 3 + 1];
        float r2 = rel_pos[(size_t)e * 3 + 2];
        float dd = dist[e];
        uint2 rec;
        rec.x = ((unsigned)d << 16) | (unsigned)sv;
        rec.y = enc_fp8(r0) | (enc_fp8(r1) << 8) | (enc_fp8(r2) << 16) |
                (enc_fp8(dd) << 24);
        int pos = atomicAdd(&cursor[d], 1);
        recs[pos] = rec;
    }
}

// ---------------------------------------------------------------------------
// Fully fused edge kernel, CSR-ordered (64 edges/block, 256 threads).
// phase0: coalesced 8B record load + fp8 decode.
// phase1: X1 = silu(Pa[dst]+Pb[src]+rp-term+b1) -> LDS.
// phase2: layer2 MFMA (W2 frags from L2-resident global).
// phase3: layer3 dot -> s_sc (LDS atomics).
// phase5: wave w owns CSR slots [w*16,w*16+16): batched gathers + boundary
//         flushes (atomics into out numerator + den).
// ---------------------------------------------------------------------------
__global__ __launch_bounds__(256, 5) void k_fused(
    const bf16_t* __restrict__ pcat, const bf16_t* __restrict__ w2t,
    const uint2* __restrict__ recs, const float* __restrict__ W1,
    const float* __restrict__ b1, const float* __restrict__ b2,
    const float* __restrict__ W3, const float* __restrict__ b3,
    float* __restrict__ den, float* __restrict__ outp) {
    __shared__ bf16_t Ax[64 * 136];
    __shared__ int s_dst[64];
    __shared__ int s_src[64];
    __shared__ float4 s_rp[64];
    __shared__ float s_sc[64];

    int t = threadIdx.x;
    int e0 = blockIdx.x * 64;
    if (t < 64) {
        uint2 rec = recs[e0 + t];
        s_dst[t] = (int)(rec.x >> 16);
        s_src[t] = (int)(rec.x & 0xFFFFu);
        s_rp[t] = make_float4(dec_fp8(rec.y & 0xFFu), dec_fp8((rec.y >> 8) & 0xFFu),
                              dec_fp8((rec.y >> 16) & 0xFFu), dec_fp8(rec.y >> 24));
        s_sc[t] = b3[0];
    }
    int lane = t & 63, w = t >> 6;
    int c0 = 2 * lane;
    float wA0 = W1[256 * 128 + c0], wA1 = W1[257 * 128 + c0];
    float wA2 = W1[258 * 128 + c0], wA3 = W1[259 * 128 + c0];
    float bA = b1[c0];
    float wB0 = W1[256 * 128 + c0 + 1], wB1 = W1[257 * 128 + c0 + 1];
    float wB2 = W1[258 * 128 + c0 + 1], wB3 = W1[259 * 128 + c0 + 1];
    float bB = b1[c0 + 1];
    __syncthreads();

    // phase 1: wave w assembles edges [w*16, w*16+16)
#pragma unroll 4
    for (int i = 0; i < 16; ++i) {
        int e = w * 16 + i;
        int dn = s_dst[e], sn = s_src[e];
        float4 rp = s_rp[e];
        unsigned pa = *reinterpret_cast<const unsigned*>(pcat + (size_t)dn * PCAT_N + c0);
        unsigned pb = *reinterpret_cast<const unsigned*>(pcat + (size_t)sn * PCAT_N + 128 + c0);
        float x0 = bf2f_lo(pa) + bf2f_lo(pb) +
                   rp.x * wA0 + rp.y * wA1 + rp.z * wA2 + rp.w * wA3 + bA;
        float x1 = bf2f_hi(pa) + bf2f_hi(pb) +
                   rp.x * wB0 + rp.y * wB1 + rp.z * wB2 + rp.w * wB3 + bB;
        float y0 = silu_f(x0), y1 = silu_f(x1);
        unsigned pk = (unsigned)f2bf_rne(y0) | ((unsigned)f2bf_rne(y1) << 16);
        *reinterpret_cast<unsigned*>(Ax + e * 136 + c0) = pk;
    }
    __syncthreads();

    // phase 2: wave w computes cols [w*32, w*32+32) for all 64 edges
    f32x4 acc[4][2] = {};
#pragma unroll
    for (int kk = 0; kk < 4; ++kk) {
        bf16x8 af[4], bfr[2];
#pragma unroll
        for (int fn = 0; fn < 2; ++fn) {
            int n = w * 32 + fn * 16 + (lane & 15);
            bfr[fn] = *reinterpret_cast<const bf16x8*>(
                w2t + (size_t)n * 128 + kk * 32 + (lane >> 4) * 8);
        }
#pragma unroll
        for (int fm = 0; fm < 4; ++fm)
            af[fm] = *reinterpret_cast<const bf16x8*>(
                Ax + (fm * 16 + (lane & 15)) * 136 + kk * 32 + (lane >> 4) * 8);
#pragma unroll
        for (int fm = 0; fm < 4; ++fm)
#pragma unroll
            for (int fn = 0; fn < 2; ++fn)
                acc[fm][fn] = __builtin_amdgcn_mfma_f32_16x16x32_bf16(
                    af[fm], bfr[fn], acc[fm][fn], 0, 0, 0);
    }

    // phase 3: layer3 (silu + dot W3), 16-lane reduce, LDS combine
    float w3v[2], b2v[2];
#pragma unroll
    for (int fn = 0; fn < 2; ++fn) {
        int n = w * 32 + fn * 16 + (lane & 15);
        w3v[fn] = W3[n];
        b2v[fn] = b2[n];
    }
#pragma unroll
    for (int fm = 0; fm < 4; ++fm) {
        float pj[4] = {0.f, 0.f, 0.f, 0.f};
#pragma unroll
        for (int fn = 0; fn < 2; ++fn) {
#pragma unroll
            for (int j = 0; j < 4; ++j)
                pj[j] += silu_f(acc[fm][fn][j] + b2v[fn]) * w3v[fn];
        }
#pragma unroll
        for (int j = 0; j < 4; ++j) {
            float v = pj[j];
            v += __shfl_xor(v, 1);
            v += __shfl_xor(v, 2);
            v += __shfl_xor(v, 4);
            v += __shfl_xor(v, 8);
            if ((lane & 15) == 0)
                atomicAdd(&s_sc[fm * 16 + (lane >> 4) * 4 + j], v);
        }
    }
    __syncthreads();

    // phase 5: wave w aggregates its own 16 CSR slots with boundary flushes
    {
        int jb = w * 16;
        float a0 = 0.f, a1 = 0.f, ad = 0.f;
        int cur = s_dst[jb];
        for (int half = 0; half < 2; ++half) {
            float cv[8], flo[8], fhi[8];
#pragma unroll
            for (int i = 0; i < 8; ++i) {
                int j = jb + half * 8 + i;
                cv[i] = __expf(s_sc[j]);
                unsigned hv = *reinterpret_cast<const unsigned*>(
                    pcat + (size_t)s_src[j] * PCAT_N + 256 + c0);
                flo[i] = bf2f_lo(hv);
                fhi[i] = bf2f_hi(hv);
            }
#pragma unroll
            for (int i = 0; i < 8; ++i) {
                int j = jb + half * 8 + i;
                int d = s_dst[j];
                if (d != cur) {  // wave-uniform branch
                    atomicAdd(&outp[(size_t)cur * 128 + c0], a0);
                    atomicAdd(&outp[(size_t)cur * 128 + c0 + 1], a1);
                    if (lane == 0) atomicAdd(&den[cur], ad);
                    a0 = a1 = ad = 0.f;
                    cur = d;
                }
                a0 += cv[i] * flo[i];
                a1 += cv[i] * fhi[i];
                ad += cv[i];
            }
        }
        atomicAdd(&outp[(size_t)cur * 128 + c0], a0);
        atomicAdd(&outp[(size_t)cur * 128 + c0 + 1], a1);
        if (lane == 0) atomicAdd(&den[cur], ad);
    }
}

// ---------------------------------------------------------------------------
// Normalize (in place): out = h + out * rcp(den[node]+eps)
// ---------------------------------------------------------------------------
__global__ __launch_bounds__(256) void k_norm(const float* __restrict__ h,
                                              const float* __restrict__ den,
                                              float* __restrict__ outp) {
    int idx = blockIdx.x * 256 + threadIdx.x;  // one float2 per thread
    int node = idx >> 6;
    float inv = __builtin_amdgcn_rcpf(den[node] + EPSV);
    float2 n2 = *reinterpret_cast<const float2*>(outp + (size_t)idx * 2);
    float2 h2 = *reinterpret_cast<const float2*>(h + (size_t)idx * 2);
    float2 res;
    res.x = h2.x + n2.x * inv;
    res.y = h2.y + n2.y * inv;
    *reinterpret_cast<float2*>(outp + (size_t)idx * 2) = res;
}

// ---------------------------------------------------------------------------
extern "C" void kernel_launch(void* const* d_in, const int* in_sizes, int n_in,
                              void* d_out, int out_size, void* d_ws, size_t ws_size,
                              hipStream_t stream) {
    const float* h       = (const float*)d_in[0];
    const int*   eidx    = (const int*)d_in[1];
    const float* rel_pos = (const float*)d_in[2];
    const float* dist    = (const float*)d_in[3];
    const float* nw      = (const float*)d_in[4];
    const float* W1      = (const float*)d_in[5];
    const float* b1      = (const float*)d_in[6];
    const float* W2      = (const float*)d_in[7];
    const float* b2      = (const float*)d_in[8];
    const float* W3      = (const float*)d_in[9];
    const float* b3      = (const float*)d_in[10];
    const float* Wv      = (const float*)d_in[11];
    float* out = (float*)d_out;

    char* p = (char*)d_ws;
    auto carve = [&](size_t bytes) {
        char* r = p;
        p += (bytes + 255) & ~(size_t)255;
        return r;
    };
    bf16_t* pcat    = (bf16_t*)carve((size_t)N_NODES * PCAT_N * 2);
    bf16_t* wcatT   = (bf16_t*)carve(384 * 128 * 2);
    bf16_t* w2t     = (bf16_t*)carve(128 * 128 * 2);
    uint2* recs     = (uint2*)carve((size_t)N_EDGES * 8);
    int* hist       = (int*)carve((size_t)N_NODES * 4);
    int* cursor     = (int*)carve((size_t)N_NODES * 4);
    float* den      = (float*)carve((size_t)N_NODES * 4);

    hipMemsetAsync(hist, 0, (size_t)N_NODES * 4, stream);
    hipMemsetAsync(out, 0, (size_t)N_NODES * HID * 4, stream);
    k_prepw<<<256, 256, 0, stream>>>(W1, W2, Wv, wcatT, w2t);
    k_nodeproj<<<(N_NODES + 63) / 64, 256, 0, stream>>>(h, wcatT, nw, pcat,
                                                        eidx, hist);
    k_scan<<<1, 1024, 0, stream>>>(hist, cursor, den);
    k_scatter<<<2048, 256, 0, stream>>>(eidx, rel_pos, dist, cursor, recs);
    k_fused<<<N_EDGES / 64, 256, 0, stream>>>(pcat, w2t, recs, W1, b1, b2,
                                              W3, b3, den, out);
    k_norm<<<(N_NODES * HID / 2) / 256, 256, 0, stream>>>(h, den, out);
}